// Round 5
// baseline (938.253 us; speedup 1.0000x reference)
//
#include <hip/hip_runtime.h>
#include <math.h>

#define D 8
#define K 32
constexpr int BLOCK = 256;
constexpr int GRID  = 2048;          // N/(GRID*BLOCK) = 4 rows/thread
constexpr int NWAVE = BLOCK / 64;

typedef float vf4 __attribute__((ext_vector_type(4)));  // native vec for nontemporal builtin

// numpy pairwise-sum tree for n=8: ((p0+p1)+(p2+p3))+((p4+p5)+(p6+p7)),
// all roundings explicit (no contraction, no reassociation).
__device__ __forceinline__ float pairwise8_sq(const float* v) {
    float p[D];
    #pragma unroll
    for (int d = 0; d < D; ++d) p[d] = __fmul_rn(v[d], v[d]);
    return __fadd_rn(
        __fadd_rn(__fadd_rn(p[0], p[1]), __fadd_rn(p[2], p[3])),
        __fadd_rn(__fadd_rn(p[4], p[5]), __fadd_rn(p[6], p[7])));
}

__global__ __launch_bounds__(BLOCK, 4) void vq_main(
        const float* __restrict__ z,
        const float* __restrict__ cb,
        float* __restrict__ zq,
        float* __restrict__ part_sum,          // [GRID]
        unsigned int* __restrict__ part_hist,  // [K][GRID]
        int n)
{
    __shared__ float cb_s[K * D];
    __shared__ float c2_s[K];
    __shared__ unsigned int h_s[K];
    __shared__ float wsum[NWAVE];

    const int tid = threadIdx.x;
    if (tid < K * D) cb_s[tid] = cb[tid];
    if (tid < K) h_s[tid] = 0u;
    __syncthreads();
    if (tid < K) c2_s[tid] = pairwise8_sq(&cb_s[tid * D]);  // np.sum(cb*cb,1)
    __syncthreads();

    float lsum = 0.f;
    const int gtid   = blockIdx.x * BLOCK + tid;
    const int stride = BLOCK * GRID;

    for (int r = gtid; r < n; r += stride) {
        const float4* zp = (const float4*)(z + (size_t)r * D);
        float4 a = zp[0];
        float4 b = zp[1];
        float zr[D] = {a.x, a.y, a.z, a.w, b.x, b.y, b.z, b.w};

        float z2 = pairwise8_sq(zr);           // np.sum(z*z,1)

        float best = 3.4e38f;
        int   bidx = 0;
        #pragma unroll
        for (int k = 0; k < K; ++k) {
            // OpenBLAS sgemm K=8: sequential FMA chain, acc from 0 — bit-exact
            float dot = 0.f;
            #pragma unroll
            for (int d = 0; d < D; ++d)
                dot = __builtin_fmaf(zr[d], cb_s[k * D + d], dot);
            // (z2 - 2*dot) + c2, left-to-right, no contraction
            float dist = __fadd_rn(__fsub_rn(z2, __fmul_rn(2.0f, dot)), c2_s[k]);
            if (dist < best) { best = dist; bidx = k; }  // first-index tie-break
        }

        atomicAdd(&h_s[bidx], 1u);

        float o[D];
        #pragma unroll
        for (int d = 0; d < D; ++d) {
            float cq   = cb_s[bidx * D + d];
            float diff = __fsub_rn(cq, zr[d]);   // (z_q - z)
            lsum += diff * diff;
            o[d] = __fadd_rn(zr[d], diff);       // z + (z_q - z): ST rounding
        }
        // z_q is never re-read: nontemporal keeps z resident in L3
        vf4* op = (vf4*)(zq + (size_t)r * D);
        vf4 o0 = {o[0], o[1], o[2], o[3]};
        vf4 o1 = {o[4], o[5], o[6], o[7]};
        __builtin_nontemporal_store(o0, op);
        __builtin_nontemporal_store(o1, op + 1);
    }

    // wave(64) shuffle reduction of squared-error sum
    #pragma unroll
    for (int off = 32; off > 0; off >>= 1)
        lsum += __shfl_down(lsum, off, 64);
    if ((tid & 63) == 0) wsum[tid >> 6] = lsum;
    __syncthreads();
    if (tid == 0) {
        float t = 0.f;
        #pragma unroll
        for (int w = 0; w < NWAVE; ++w) t += wsum[w];
        part_sum[blockIdx.x] = t;              // plain store — no init needed
    }
    if (tid < K) part_hist[(size_t)tid * GRID + blockIdx.x] = h_s[tid];
}

__global__ __launch_bounds__(256) void vq_final(
        const float* __restrict__ part_sum,
        const unsigned int* __restrict__ part_hist,
        float* __restrict__ out, long long nd, int n)
{
    __shared__ double red[4];
    __shared__ unsigned int hred[K][8];
    __shared__ double ent_s[K];
    const int tid = threadIdx.x;

    // total squared error: 2048 partials, 8/thread, double
    double s = 0.0;
    for (int i = tid; i < GRID; i += 256) s += (double)part_sum[i];
    #pragma unroll
    for (int off = 32; off > 0; off >>= 1) s += __shfl_down(s, off, 64);
    if ((tid & 63) == 0) red[tid >> 6] = s;

    // histogram: 8 threads per k, 256 entries each (contiguous runs)
    {
        const int k = tid >> 3, j = tid & 7;
        const unsigned int* p = part_hist + (size_t)k * GRID + j * (GRID / 8);
        unsigned int c = 0;
        for (int i = 0; i < GRID / 8; ++i) c += p[i];
        hred[k][j] = c;
    }
    __syncthreads();

    if (tid < K) {
        unsigned int c = 0;
        #pragma unroll
        for (int j = 0; j < 8; ++j) c += hred[tid][j];
        double p = (double)c / (double)n;
        ent_s[tid] = p * log(p + 1e-10);       // parallel entropy terms
    }
    __syncthreads();

    if (tid == 0) {
        double S = red[0] + red[1] + red[2] + red[3];
        double ent = 0.0;
        for (int k = 0; k < K; ++k) ent += ent_s[k];
        out[nd]     = (float)(1.25 * S / (double)nd);
        out[nd + 1] = (float)exp(-ent);
    }
}

extern "C" void kernel_launch(void* const* d_in, const int* in_sizes, int n_in,
                              void* d_out, int out_size, void* d_ws, size_t ws_size,
                              hipStream_t stream)
{
    const float* z  = (const float*)d_in[0];
    const float* cb = (const float*)d_in[1];
    float* out      = (float*)d_out;

    const int n = in_sizes[0] / D;             // 2,097,152
    const long long nd = (long long)n * D;

    // ws layout: [0, GRID*4) float part_sum; [8192, +K*GRID*4) uint part_hist
    float*        part_sum  = (float*)d_ws;
    unsigned int* part_hist = (unsigned int*)((char*)d_ws + 8192);

    vq_main<<<GRID, BLOCK, 0, stream>>>(z, cb, out, part_sum, part_hist, n);
    vq_final<<<1, 256, 0, stream>>>(part_sum, part_hist, out, nd, n);
}

// Round 6
// 131.809 us; speedup vs baseline: 7.1183x; 7.1183x over previous
//
#include <hip/hip_runtime.h>
#include <math.h>

#define D 8
#define K 32
constexpr int BLOCK = 256;
constexpr int GRID  = 2048;          // 4 rows/thread
constexpr int NWAVE = BLOCK / 64;

typedef float vf4 __attribute__((ext_vector_type(4)));

// numpy pairwise-sum tree for n=8: ((p0+p1)+(p2+p3))+((p4+p5)+(p6+p7)),
// all roundings explicit (no contraction, no reassociation).
__device__ __forceinline__ float pairwise8_sq(const float* v) {
    float p[D];
    #pragma unroll
    for (int d = 0; d < D; ++d) p[d] = __fmul_rn(v[d], v[d]);
    return __fadd_rn(
        __fadd_rn(__fadd_rn(p[0], p[1]), __fadd_rn(p[2], p[3])),
        __fadd_rn(__fadd_rn(p[4], p[5]), __fadd_rn(p[6], p[7])));
}

// launch_bounds(256,3): VGPR cap 170 — generous vs the ~110 live set after
// unroll-limiting, so NO spill (R5's forced 128-cap spilled 2.5 GB to scratch).
__global__ __launch_bounds__(BLOCK, 3) void vq_main(
        const float* __restrict__ z,
        const float* __restrict__ cb,
        float* __restrict__ zq,
        float* __restrict__ part_sum,          // [GRID]
        unsigned int* __restrict__ part_hist,  // [K][GRID]
        int n)
{
    __shared__ float cb_s[K * D];
    __shared__ float c2_s[K];
    __shared__ unsigned int h_s[K];
    __shared__ float wsum[NWAVE];

    const int tid = threadIdx.x;
    if (tid < K * D) cb_s[tid] = cb[tid];
    if (tid < K) h_s[tid] = 0u;
    __syncthreads();
    if (tid < K) c2_s[tid] = pairwise8_sq(&cb_s[tid * D]);  // np.sum(cb*cb,1)
    __syncthreads();

    float lsum = 0.f;
    const int gtid   = blockIdx.x * BLOCK + tid;
    const int stride = BLOCK * GRID;

    for (int r = gtid; r < n; r += stride) {
        const float4* zp = (const float4*)(z + (size_t)r * D);
        float4 a = zp[0];
        float4 b = zp[1];
        float zr[D] = {a.x, a.y, a.z, a.w, b.x, b.y, b.z, b.w};

        float z2 = pairwise8_sq(zr);           // np.sum(z*z,1)

        float best = 3.4e38f;
        int   bidx = 0;
        // unroll 8: caps live LDS stages at 8 codewords (~64 floats) instead
        // of 32 (~256 floats) — keeps VGPRs ~110, ILP still 8-wide.
        #pragma unroll 8
        for (int k = 0; k < K; ++k) {
            // OpenBLAS sgemm K=8: sequential FMA chain, acc from 0 — bit-exact
            float dot = 0.f;
            #pragma unroll
            for (int d = 0; d < D; ++d)
                dot = __builtin_fmaf(zr[d], cb_s[k * D + d], dot);
            // (z2 - 2*dot) + c2, left-to-right, no contraction
            float dist = __fadd_rn(__fsub_rn(z2, __fmul_rn(2.0f, dot)), c2_s[k]);
            if (dist < best) { best = dist; bidx = k; }  // first-index tie-break
        }

        atomicAdd(&h_s[bidx], 1u);

        float o[D];
        #pragma unroll
        for (int d = 0; d < D; ++d) {
            float cq   = cb_s[bidx * D + d];
            float diff = __fsub_rn(cq, zr[d]);   // (z_q - z)
            lsum += diff * diff;
            o[d] = __fadd_rn(zr[d], diff);       // z + (z_q - z): ST rounding
        }
        // z_q is never re-read: nontemporal keeps z resident in L3
        vf4* op = (vf4*)(zq + (size_t)r * D);
        vf4 o0 = {o[0], o[1], o[2], o[3]};
        vf4 o1 = {o[4], o[5], o[6], o[7]};
        __builtin_nontemporal_store(o0, op);
        __builtin_nontemporal_store(o1, op + 1);
    }

    // wave(64) shuffle reduction of squared-error sum
    #pragma unroll
    for (int off = 32; off > 0; off >>= 1)
        lsum += __shfl_down(lsum, off, 64);
    if ((tid & 63) == 0) wsum[tid >> 6] = lsum;
    __syncthreads();
    if (tid == 0) {
        float t = 0.f;
        #pragma unroll
        for (int w = 0; w < NWAVE; ++w) t += wsum[w];
        part_sum[blockIdx.x] = t;
    }
    if (tid < K) part_hist[(size_t)tid * GRID + blockIdx.x] = h_s[tid];
}

__global__ __launch_bounds__(1024) void vq_final(
        const float* __restrict__ part_sum,
        const unsigned int* __restrict__ part_hist,
        float* __restrict__ out, long long nd, int n)
{
    __shared__ double red[16];
    __shared__ unsigned int hsum[K];
    __shared__ double ent_s[K];
    const int tid = threadIdx.x;

    // total squared error: 2048 partials, 2/thread, f64 accumulate
    double s = 0.0;
    for (int i = tid; i < GRID; i += 1024) s += (double)part_sum[i];
    #pragma unroll
    for (int off = 32; off > 0; off >>= 1) s += __shfl_down(s, off, 64);
    if ((tid & 63) == 0) red[tid >> 6] = s;

    // histogram: 32 threads per bin k, coalesced strided loads, subgroup reduce
    {
        const int k = tid >> 5, j = tid & 31;
        const unsigned int* p = part_hist + (size_t)k * GRID;
        unsigned int c = 0;
        for (int i = j; i < GRID; i += 32) c += p[i];
        #pragma unroll
        for (int off = 16; off > 0; off >>= 1) c += __shfl_down(c, off, 32);
        if (j == 0) hsum[k] = c;
    }
    __syncthreads();

    if (tid < K) {
        double p = (double)hsum[tid] / (double)n;
        ent_s[tid] = p * log(p + 1e-10);
    }
    __syncthreads();

    if (tid == 0) {
        double S = 0.0;
        #pragma unroll
        for (int w = 0; w < 16; ++w) S += red[w];
        double ent = 0.0;
        for (int k = 0; k < K; ++k) ent += ent_s[k];
        out[nd]     = (float)(1.25 * S / (double)nd);
        out[nd + 1] = (float)exp(-ent);
    }
}

extern "C" void kernel_launch(void* const* d_in, const int* in_sizes, int n_in,
                              void* d_out, int out_size, void* d_ws, size_t ws_size,
                              hipStream_t stream)
{
    const float* z  = (const float*)d_in[0];
    const float* cb = (const float*)d_in[1];
    float* out      = (float*)d_out;

    const int n = in_sizes[0] / D;             // 2,097,152
    const long long nd = (long long)n * D;

    // ws layout: [0, GRID*4) float part_sum; [8192, +K*GRID*4) uint part_hist
    float*        part_sum  = (float*)d_ws;
    unsigned int* part_hist = (unsigned int*)((char*)d_ws + 8192);

    vq_main<<<GRID, BLOCK, 0, stream>>>(z, cb, out, part_sum, part_hist, n);
    vq_final<<<1, 1024, 0, stream>>>(part_sum, part_hist, out, nd, n);
}

// Round 7
// 130.077 us; speedup vs baseline: 7.2130x; 1.0133x over previous
//
#include <hip/hip_runtime.h>
#include <math.h>

#define D 8
#define K 32
constexpr int BLOCK = 256;
constexpr int ROWS  = 4;                       // rows staged per thread
constexpr int GRID  = 2048;                    // GRID*BLOCK*ROWS == N
constexpr int NWAVE = BLOCK / 64;

typedef float vf4 __attribute__((ext_vector_type(4)));

// numpy pairwise-sum tree for n=8: ((p0+p1)+(p2+p3))+((p4+p5)+(p6+p7)),
// all roundings explicit (no contraction, no reassociation).
__device__ __forceinline__ float pairwise8_sq(const float* v) {
    float p[D];
    #pragma unroll
    for (int d = 0; d < D; ++d) p[d] = __fmul_rn(v[d], v[d]);
    return __fadd_rn(
        __fadd_rn(__fadd_rn(p[0], p[1]), __fadd_rn(p[2], p[3])),
        __fadd_rn(__fadd_rn(p[4], p[5]), __fadd_rn(p[6], p[7])));
}

__global__ __launch_bounds__(BLOCK) void vq_main(
        const float* __restrict__ z,
        const float* __restrict__ cb,
        float* __restrict__ zq,
        float* __restrict__ part_sum,          // [GRID]
        unsigned int* __restrict__ part_hist,  // [K][GRID]
        int n)
{
    __shared__ float cb_s[K * D];
    __shared__ float c2_s[K];
    __shared__ unsigned int h_s[K];
    __shared__ float wsum[NWAVE];

    const int tid = threadIdx.x;
    if (tid < K * D) cb_s[tid] = cb[tid];
    if (tid < K) h_s[tid] = 0u;
    __syncthreads();
    if (tid < K) c2_s[tid] = pairwise8_sq(&cb_s[tid * D]);  // np.sum(cb*cb,1)
    __syncthreads();

    // block owns 1024 contiguous rows; thread owns base+{0,256,512,768}
    const int base = blockIdx.x * (BLOCK * ROWS) + tid;

    float zr[ROWS][D];
    float z2[ROWS];
    #pragma unroll
    for (int r = 0; r < ROWS; ++r) {
        const float4* zp = (const float4*)(z + (size_t)(base + r * BLOCK) * D);
        float4 a = zp[0];
        float4 b = zp[1];
        zr[r][0]=a.x; zr[r][1]=a.y; zr[r][2]=a.z; zr[r][3]=a.w;
        zr[r][4]=b.x; zr[r][5]=b.y; zr[r][6]=b.z; zr[r][7]=b.w;
        z2[r] = pairwise8_sq(zr[r]);           // np.sum(z*z,1)
    }

    float best[ROWS];
    int   bidx[ROWS];
    #pragma unroll
    for (int r = 0; r < ROWS; ++r) { best[r] = 3.4e38f; bidx[r] = 0; }

    // k outer / rows inner: one cb-row LDS load serves ROWS dist computations.
    // unroll 4 => 16 independent FMA chains in flight, ~100 VGPR live set.
    #pragma unroll 4
    for (int k = 0; k < K; ++k) {
        float c[D];
        #pragma unroll
        for (int d = 0; d < D; ++d) c[d] = cb_s[k * D + d];
        const float c2 = c2_s[k];
        #pragma unroll
        for (int r = 0; r < ROWS; ++r) {
            // OpenBLAS sgemm K=8: sequential FMA chain from 0 — bit-exact
            float dot = 0.f;
            #pragma unroll
            for (int d = 0; d < D; ++d)
                dot = __builtin_fmaf(zr[r][d], c[d], dot);
            // (z2 - 2*dot) + c2, left-to-right, no contraction
            float dist = __fadd_rn(__fsub_rn(z2[r], __fmul_rn(2.0f, dot)), c2);
            if (dist < best[r]) { best[r] = dist; bidx[r] = k; }  // first-index ties
        }
    }

    float lsum = 0.f;
    #pragma unroll
    for (int r = 0; r < ROWS; ++r) {
        atomicAdd(&h_s[bidx[r]], 1u);
        float o[D];
        #pragma unroll
        for (int d = 0; d < D; ++d) {
            float cq   = cb_s[bidx[r] * D + d];
            float diff = __fsub_rn(cq, zr[r][d]);   // (z_q - z)
            lsum += diff * diff;
            o[d] = __fadd_rn(zr[r][d], diff);       // z + (z_q - z): ST rounding
        }
        vf4* op = (vf4*)(zq + (size_t)(base + r * BLOCK) * D);
        vf4 o0 = {o[0], o[1], o[2], o[3]};
        vf4 o1 = {o[4], o[5], o[6], o[7]};
        __builtin_nontemporal_store(o0, op);        // z_q never re-read
        __builtin_nontemporal_store(o1, op + 1);
    }

    // wave(64) shuffle reduction of squared-error sum
    #pragma unroll
    for (int off = 32; off > 0; off >>= 1)
        lsum += __shfl_down(lsum, off, 64);
    if ((tid & 63) == 0) wsum[tid >> 6] = lsum;
    __syncthreads();
    if (tid == 0) {
        float t = 0.f;
        #pragma unroll
        for (int w = 0; w < NWAVE; ++w) t += wsum[w];
        part_sum[blockIdx.x] = t;
    }
    if (tid < K) part_hist[(size_t)tid * GRID + blockIdx.x] = h_s[tid];
}

__global__ __launch_bounds__(1024) void vq_final(
        const float* __restrict__ part_sum,
        const unsigned int* __restrict__ part_hist,
        float* __restrict__ out, long long nd, int n)
{
    __shared__ double red[16];
    __shared__ unsigned int hsum[K];
    __shared__ double ent_s[K];
    const int tid = threadIdx.x;

    // total squared error: 2048 partials, f64 accumulate
    double s = 0.0;
    for (int i = tid; i < GRID; i += 1024) s += (double)part_sum[i];
    #pragma unroll
    for (int off = 32; off > 0; off >>= 1) s += __shfl_down(s, off, 64);
    if ((tid & 63) == 0) red[tid >> 6] = s;

    // histogram: 32 threads per bin k, coalesced strided loads, subgroup reduce
    {
        const int k = tid >> 5, j = tid & 31;
        const unsigned int* p = part_hist + (size_t)k * GRID;
        unsigned int c = 0;
        for (int i = j; i < GRID; i += 32) c += p[i];
        #pragma unroll
        for (int off = 16; off > 0; off >>= 1) c += __shfl_down(c, off, 32);
        if (j == 0) hsum[k] = c;
    }
    __syncthreads();

    if (tid < K) {
        double p = (double)hsum[tid] / (double)n;
        ent_s[tid] = p * log(p + 1e-10);
    }
    __syncthreads();

    if (tid == 0) {
        double S = 0.0;
        #pragma unroll
        for (int w = 0; w < 16; ++w) S += red[w];
        double ent = 0.0;
        for (int k = 0; k < K; ++k) ent += ent_s[k];
        out[nd]     = (float)(1.25 * S / (double)nd);
        out[nd + 1] = (float)exp(-ent);
    }
}

extern "C" void kernel_launch(void* const* d_in, const int* in_sizes, int n_in,
                              void* d_out, int out_size, void* d_ws, size_t ws_size,
                              hipStream_t stream)
{
    const float* z  = (const float*)d_in[0];
    const float* cb = (const float*)d_in[1];
    float* out      = (float*)d_out;

    const int n = in_sizes[0] / D;             // 2,097,152 == GRID*BLOCK*ROWS
    const long long nd = (long long)n * D;

    // ws layout: [0, GRID*4) float part_sum; [8192, +K*GRID*4) uint part_hist
    float*        part_sum  = (float*)d_ws;
    unsigned int* part_hist = (unsigned int*)((char*)d_ws + 8192);

    vq_main<<<GRID, BLOCK, 0, stream>>>(z, cb, out, part_sum, part_hist, n);
    vq_final<<<1, 1024, 0, stream>>>(part_sum, part_hist, out, nd, n);
}